// Round 1
// baseline (1891.368 us; speedup 1.0000x reference)
//
#include <hip/hip_runtime.h>
#include <cmath>

#define BATCH 256
#define SEQL  128
#define NBD   6
#define FPC   200
#define BL    (BATCH*SEQL)   /* 32768 */
#define NEGV  -9e8f

__device__ __forceinline__ float wave_sum(float v) {
#pragma unroll
    for (int o = 32; o > 0; o >>= 1) v += __shfl_xor(v, o);
    return v;
}
__device__ __forceinline__ float leakyf(float x){ return x > 0.f ? x : 0.01f*x; }

// ---------------------------------------------------------------------------
// Generic tiled GEMM: C[m,n] = act( sum_k A[m,k]*W[n,k] + bias[n]*rowscale[m] )
// A: [M,lda], W: [N,ldw] (row-major, dot over trailing dim), C: [M,ldc]
// ACT: 0=none, 1=leaky_relu(0.01), 2=elu
// ---------------------------------------------------------------------------
template<int ACT, bool RS>
__global__ __launch_bounds__(256)
void gemm_bt(const float* __restrict__ A, int lda,
             const float* __restrict__ W, int ldw,
             const float* __restrict__ bias,
             const float* __restrict__ rowscale,
             float* __restrict__ C, int ldc,
             int M, int N, int K)
{
    __shared__ float As[16][68];
    __shared__ float Ws[16][68];
    const int tid = threadIdx.x;
    const int bm = blockIdx.x * 64;
    const int bn = blockIdx.y * 64;
    const int tx = tid & 15;       // n dir (4 cols each)
    const int ty = tid >> 4;       // m dir (4 rows each)
    const int lr = tid >> 2;       // staging row 0..63
    const int lk = (tid & 3) << 2; // staging k 0,4,8,12
    float acc[4][4] = {};

    for (int k0 = 0; k0 < K; k0 += 16) {
        float a0=0.f,a1=0.f,a2=0.f,a3=0.f, w0=0.f,w1=0.f,w2=0.f,w3=0.f;
        {
            const int rem = K - (k0 + lk);
            const int m = bm + lr;
            if (m < M) {
                const float* p = A + (size_t)m*lda + k0 + lk;
                if (rem > 0) a0 = p[0];
                if (rem > 1) a1 = p[1];
                if (rem > 2) a2 = p[2];
                if (rem > 3) a3 = p[3];
            }
            const int n = bn + lr;
            if (n < N) {
                const float* p = W + (size_t)n*ldw + k0 + lk;
                if (rem > 0) w0 = p[0];
                if (rem > 1) w1 = p[1];
                if (rem > 2) w2 = p[2];
                if (rem > 3) w3 = p[3];
            }
        }
        __syncthreads();
        As[lk+0][lr]=a0; As[lk+1][lr]=a1; As[lk+2][lr]=a2; As[lk+3][lr]=a3;
        Ws[lk+0][lr]=w0; Ws[lk+1][lr]=w1; Ws[lk+2][lr]=w2; Ws[lk+3][lr]=w3;
        __syncthreads();
#pragma unroll
        for (int kk = 0; kk < 16; kk++) {
            const float4 av4 = *reinterpret_cast<const float4*>(&As[kk][ty<<2]);
            const float4 wv4 = *reinterpret_cast<const float4*>(&Ws[kk][tx<<2]);
            const float av[4] = {av4.x, av4.y, av4.z, av4.w};
            const float wv[4] = {wv4.x, wv4.y, wv4.z, wv4.w};
#pragma unroll
            for (int i=0;i<4;i++)
#pragma unroll
                for (int j=0;j<4;j++)
                    acc[i][j] = fmaf(av[i], wv[j], acc[i][j]);
        }
    }
#pragma unroll
    for (int i=0;i<4;i++){
        const int m = bm + (ty<<2) + i;
        if (m >= M) continue;
        const float rs = RS ? rowscale[m] : 1.f;
#pragma unroll
        for (int j=0;j<4;j++){
            const int n = bn + (tx<<2) + j;
            if (n >= N) continue;
            float v = acc[i][j] + bias[n]*rs;
            if (ACT==1) v = leakyf(v);
            else if (ACT==2) v = v > 0.f ? v : (expf(v)-1.f);
            C[(size_t)m*ldc + n] = v;
        }
    }
}

// ---------------------------------------------------------------------------
// Build concat(atom_nb, bond_nb) rows: acat[(atom*6+j), 0:49]
// ---------------------------------------------------------------------------
__global__ __launch_bounds__(64)
void gather_cat(const float* __restrict__ atom_list, const float* __restrict__ bond_list,
                const int* __restrict__ adl, const int* __restrict__ bdl,
                float* __restrict__ acat)
{
    const int row = blockIdx.x;       // atom*6 + j, 0..196607
    const int t = threadIdx.x;
    if (t >= 49) return;
    const int atom = row / 6;         // b*L + l
    const int b = atom >> 7;          // /128
    float v;
    if (t < 39) { const int ai = adl[row]; v = atom_list[((size_t)(b*SEQL + ai))*39 + t]; }
    else        { const int bi = bdl[row]; v = bond_list[((size_t)(b*SEQL + bi))*10 + (t-39)]; }
    acat[(size_t)row*49 + t] = v;
}

// ---------------------------------------------------------------------------
// Per-atom neighbor attention (one wave per atom).
// Computes wnb[atom,:] = sum_j aw_j * nb_j[:]   and s_aw[atom] = sum_j aw_j
// D0: nb rows from nbbuf [atom*6+j]; else gather rows of act.
// ---------------------------------------------------------------------------
template<bool D0>
__global__ __launch_bounds__(64)
void attn_radius(const float* __restrict__ cur, const float* __restrict__ nbsrc,
                 const int* __restrict__ adl,
                 const float* __restrict__ aw_, const float* __restrict__ ab_,
                 float* __restrict__ wnb, float* __restrict__ s_aw)
{
    const int atom = blockIdx.x;
    const int lane = threadIdx.x;
    const float* crow = cur + (size_t)atom*FPC;
    int   cc[4]; bool val[4];
    float a2[4];
    float s1p = 0.f;
#pragma unroll
    for (int r=0;r<4;r++){
        const int c = lane + 64*r; cc[r]=c; val[r] = (c < FPC);
        const float x  = val[r] ? crow[c]      : 0.f;
        const float w1 = val[r] ? aw_[c]       : 0.f;
        a2[r]          = val[r] ? aw_[FPC + c] : 0.f;
        s1p = fmaf(w1, x, s1p);
    }
    const float s1 = wave_sum(s1p);
    const int base = atom & ~(SEQL-1);   // b*L
    const float ab = ab_[0];
    float nbr[NBD][4]; float score[NBD]; int idx[NBD];
#pragma unroll
    for (int j=0;j<NBD;j++){
        const int id = adl[atom*NBD + j]; idx[j]=id;
        const float* nrow = D0 ? nbsrc + ((size_t)atom*NBD + j)*FPC
                               : nbsrc + ((size_t)(base + id))*FPC;
        float s2p = 0.f;
#pragma unroll
        for (int r=0;r<4;r++){
            const float v = val[r] ? nrow[cc[r]] : 0.f;
            nbr[j][r]=v; s2p = fmaf(a2[r], v, s2p);
        }
        const float s2 = wave_sum(s2p);
        float sc = leakyf(s1 + s2 + ab);
        score[j] = sc + (id == SEQL-1 ? NEGV : 0.f);
    }
    float mx = score[0];
#pragma unroll
    for (int j=1;j<NBD;j++) mx = fmaxf(mx, score[j]);
    float e[NBD], sum = 0.f;
#pragma unroll
    for (int j=0;j<NBD;j++){ e[j] = expf(score[j]-mx); sum += e[j]; }
    const float inv = 1.f/sum;
    float w[NBD], saw = 0.f;
#pragma unroll
    for (int j=0;j<NBD;j++){ w[j] = e[j]*inv*(idx[j]==SEQL-1 ? 0.f : 1.f); saw += w[j]; }
#pragma unroll
    for (int r=0;r<4;r++){
        if (val[r]){
            float acc = 0.f;
#pragma unroll
            for (int j=0;j<NBD;j++) acc = fmaf(w[j], nbr[j][r], acc);
            wnb[(size_t)atom*FPC + cc[r]] = acc;
        }
    }
    if (lane==0) s_aw[atom] = saw;
}

// ---------------------------------------------------------------------------
// GRU gate combine: h = (1-z)*n + z*h ; act = relu(h)
// gi/gh rows of 600 (r|z|n), h/act rows of 200. total = rows*200
// ---------------------------------------------------------------------------
__global__ __launch_bounds__(256)
void gru_combine(const float* __restrict__ gi, const float* __restrict__ gh,
                 float* __restrict__ h, float* __restrict__ act, int total)
{
    const int i = blockIdx.x*blockDim.x + threadIdx.x;
    if (i >= total) return;
    const int m = i / FPC, c = i - m*FPC;
    const size_t g = (size_t)m*600 + c;
    const float ir = gi[g], iz = gi[g+200], in_ = gi[g+400];
    const float hr = gh[g], hz = gh[g+200], hn = gh[g+400];
    const float r = 1.f/(1.f+expf(-(ir+hr)));
    const float z = 1.f/(1.f+expf(-(iz+hz)));
    const float n = tanhf(in_ + r*hn);
    const float hv = h[i];
    const float out = (1.f-z)*n + z*hv;
    h[i] = out;
    act[i] = out > 0.f ? out : 0.f;
}

// ---------------------------------------------------------------------------
// mol_feature[b,c] = sum_l act[b,l,c]*amask[b,l]; act_mol = relu
// ---------------------------------------------------------------------------
__global__ __launch_bounds__(256)
void mol_reduce(const float* __restrict__ act, const float* __restrict__ amask,
                float* __restrict__ molf, float* __restrict__ amol)
{
    const int b = blockIdx.x, c = threadIdx.x;
    if (c >= FPC) return;
    float s = 0.f;
    for (int l=0;l<SEQL;l++) s = fmaf(act[((size_t)(b*SEQL+l))*FPC + c], amask[b*SEQL+l], s);
    molf[b*FPC+c] = s;
    amol[b*FPC+c] = s > 0.f ? s : 0.f;
}

// ---------------------------------------------------------------------------
// Molecular attention: wact[b,:] = sum_l mw_l*act[b,l,:]; s_mw[b] = sum mw
// ---------------------------------------------------------------------------
__global__ __launch_bounds__(256)
void attn_mol(const float* __restrict__ amol, const float* __restrict__ act,
              const float* __restrict__ amask,
              const float* __restrict__ maw, const float* __restrict__ mab,
              float* __restrict__ wact, float* __restrict__ s_mw)
{
    __shared__ float red[256];
    __shared__ float sc[SEQL];
    __shared__ float mw[SEQL];
    const int b = blockIdx.x, tid = threadIdx.x;
    red[tid] = (tid < FPC) ? maw[tid]*amol[b*FPC+tid] : 0.f;
    __syncthreads();
    for (int s=128; s>0; s>>=1){ if (tid < s) red[tid] += red[tid+s]; __syncthreads(); }
    const float s1 = red[0];
    __syncthreads();
    if (tid < SEQL) {
        const float* arow = act + ((size_t)(b*SEQL + tid))*FPC;
        float s2 = 0.f;
        for (int c=0;c<FPC;c++) s2 = fmaf(maw[FPC+c], arow[c], s2);
        const float am = amask[b*SEQL+tid];
        sc[tid] = leakyf(s1 + s2 + mab[0]) + (am == 0.f ? NEGV : 0.f);
    }
    __syncthreads();
    float mx = -1e30f;
    for (int l=0;l<SEQL;l++) mx = fmaxf(mx, sc[l]);
    float sum = 0.f;
    for (int l=0;l<SEQL;l++) sum += expf(sc[l]-mx);
    const float inv = 1.f/sum;
    if (tid < SEQL) mw[tid] = expf(sc[tid]-mx)*inv*amask[b*SEQL+tid];
    __syncthreads();
    float smw = 0.f;
    for (int l=0;l<SEQL;l++) smw += mw[l];
    if (tid < FPC) {
        float acc = 0.f;
        for (int l=0;l<SEQL;l++) acc = fmaf(mw[l], act[((size_t)(b*SEQL+l))*FPC + tid], acc);
        wact[b*FPC+tid] = acc;
    }
    if (tid==0) s_mw[b] = smw;
}

__global__ __launch_bounds__(64)
void out_proj(const float* __restrict__ molf, const float* __restrict__ ow,
              const float* __restrict__ ob, float* __restrict__ out)
{
    const int b = blockIdx.x, lane = threadIdx.x;
    float p = 0.f;
    for (int c=lane;c<FPC;c+=64) p = fmaf(molf[b*FPC+c], ow[c], p);
    p = wave_sum(p);
    if (lane==0) out[b] = p + ob[0];
}

__global__ __launch_bounds__(256)
void copy_f32(const float* __restrict__ src, float* __restrict__ dst, int n)
{
    const int i = blockIdx.x*blockDim.x + threadIdx.x;
    if (i < n) dst[i] = src[i];
}

// ---------------------------------------------------------------------------
extern "C" void kernel_launch(void* const* d_in, const int* in_sizes, int n_in,
                              void* d_out, int out_size, void* d_ws, size_t ws_size,
                              hipStream_t stream)
{
    const float* atom_list = (const float*)d_in[0];
    const float* bond_list = (const float*)d_in[1];
    const int*   adl       = (const int*)d_in[2];
    const int*   bdl       = (const int*)d_in[3];
    const float* amask     = (const float*)d_in[4];
    const float* atom_fc_w = (const float*)d_in[5];
    const float* atom_fc_b = (const float*)d_in[6];
    const float* nb_fc_w   = (const float*)d_in[7];
    const float* nb_fc_b   = (const float*)d_in[8];
    const float* align_w   = (const float*)d_in[9];
    const float* align_b   = (const float*)d_in[10];
    const float* attend_w  = (const float*)d_in[11];
    const float* attend_b  = (const float*)d_in[12];
    const float* gru_wih   = (const float*)d_in[13];
    const float* gru_whh   = (const float*)d_in[14];
    const float* gru_bih   = (const float*)d_in[15];
    const float* gru_bhh   = (const float*)d_in[16];
    const float* mol_align_w  = (const float*)d_in[17];
    const float* mol_align_b  = (const float*)d_in[18];
    const float* mol_attend_w = (const float*)d_in[19];
    const float* mol_attend_b = (const float*)d_in[20];
    const float* mol_gru_wih  = (const float*)d_in[21];
    const float* mol_gru_whh  = (const float*)d_in[22];
    const float* mol_gru_bih  = (const float*)d_in[23];
    const float* mol_gru_bhh  = (const float*)d_in[24];
    const float* output_w  = (const float*)d_in[25];
    const float* output_b  = (const float*)d_in[26];

    float* ws   = (float*)d_ws;
    float* h    = ws;                  // [32768,200]
    float* act  = h   + 6553600;       // [32768,200]
    float* wnb  = act + 6553600;       // [32768,200]
    float* ctx  = wnb + 6553600;       // [32768,200]
    float* gi   = ctx + 6553600;       // [32768,600]
    float* gh   = gi  + 19660800;      // [32768,600]
    float* nbb  = gi;                  // alias: [196608,200] spans gi+gh, dead before gi written
    float* acat = wnb;                 // alias: [196608,49] fits in wnb+ctx, dead before wnb written
    float* s_aw = gh  + 19660800;      // [32768]
    float* molf = s_aw + 32768;        // [256,200]
    float* amol = molf + 51200;
    float* wact = amol + 51200;
    float* s_mw = wact + 51200;        // [256]
    float* mctx = s_mw + 256;          // [256,200]
    float* mgi  = mctx + 51200;        // [256,600]
    float* mgh  = mgi  + 153600;

    const dim3 blk(256);

    // atom_feature = leaky(atom_list @ atom_fc_w.T + b) -> h
    gemm_bt<1,false><<<dim3(512,4), blk, 0, stream>>>(
        atom_list, 39, atom_fc_w, 39, atom_fc_b, nullptr, h, FPC, BL, FPC, 39);

    // neighbor features (d=0 only)
    gather_cat<<<BL*NBD, 64, 0, stream>>>(atom_list, bond_list, adl, bdl, acat);
    gemm_bt<1,false><<<dim3(3072,4), blk, 0, stream>>>(
        acat, 49, nb_fc_w, 49, nb_fc_b, nullptr, nbb, FPC, BL*NBD, FPC, 49);

    for (int d=0; d<3; d++) {
        if (d==0)
            attn_radius<true ><<<BL, 64, 0, stream>>>(h,   nbb, adl, align_w,         align_b,     wnb, s_aw);
        else
            attn_radius<false><<<BL, 64, 0, stream>>>(act, act, adl, align_w + d*400, align_b + d, wnb, s_aw);
        // ctx = elu(wnb @ attend_w[d].T + s_aw*attend_b[d])
        gemm_bt<2,true><<<dim3(512,4), blk, 0, stream>>>(
            wnb, FPC, attend_w + d*40000, FPC, attend_b + d*FPC, s_aw, ctx, FPC, BL, FPC, FPC);
        // gi = ctx @ wih.T + bih ; gh = h @ whh.T + bhh
        gemm_bt<0,false><<<dim3(512,10), blk, 0, stream>>>(
            ctx, FPC, gru_wih + d*120000, FPC, gru_bih + d*600, nullptr, gi, 600, BL, 600, FPC);
        gemm_bt<0,false><<<dim3(512,10), blk, 0, stream>>>(
            h,   FPC, gru_whh + d*120000, FPC, gru_bhh + d*600, nullptr, gh, 600, BL, 600, FPC);
        gru_combine<<<25600, 256, 0, stream>>>(gi, gh, h, act, BL*FPC);
    }

    // molecule phase
    mol_reduce<<<BATCH, 256, 0, stream>>>(act, amask, molf, amol);
    for (int t=0; t<2; t++) {
        attn_mol<<<BATCH, 256, 0, stream>>>(amol, act, amask, mol_align_w, mol_align_b, wact, s_mw);
        gemm_bt<2,true><<<dim3(4,4), blk, 0, stream>>>(
            wact, FPC, mol_attend_w, FPC, mol_attend_b, s_mw, mctx, FPC, BATCH, FPC, FPC);
        gemm_bt<0,false><<<dim3(4,10), blk, 0, stream>>>(
            mctx, FPC, mol_gru_wih, FPC, mol_gru_bih, nullptr, mgi, 600, BATCH, 600, FPC);
        gemm_bt<0,false><<<dim3(4,10), blk, 0, stream>>>(
            molf, FPC, mol_gru_whh, FPC, mol_gru_bhh, nullptr, mgh, 600, BATCH, 600, FPC);
        gru_combine<<<200, 256, 0, stream>>>(mgi, mgh, molf, amol, BATCH*FPC);
    }

    // outputs: atom_feature (h) then mol_prediction
    float* out = (float*)d_out;
    copy_f32<<<25600, 256, 0, stream>>>(h, out, BL*FPC);
    out_proj<<<BATCH, 64, 0, stream>>>(molf, output_w, output_b, out + BL*FPC);
}

// Round 4
// 974.437 us; speedup vs baseline: 1.9410x; 1.9410x over previous
//
#include <hip/hip_runtime.h>
#include <cmath>

#define BATCH 256
#define SEQL  128
#define NBD   6
#define FPC   200
#define BL    (BATCH*SEQL)   /* 32768 */
#define NEGV  -9e8f

typedef __attribute__((ext_vector_type(8))) short short8;
typedef __attribute__((ext_vector_type(4))) float f32x4;

__device__ __forceinline__ float wave_sum(float v) {
#pragma unroll
    for (int o = 32; o > 0; o >>= 1) v += __shfl_xor(v, o);
    return v;
}
__device__ __forceinline__ float leakyf(float x){ return x > 0.f ? x : 0.01f*x; }
// bf16 round-to-nearest-even (finite inputs)
__device__ __forceinline__ unsigned short f2bf(float f){
    unsigned int x = __float_as_uint(f);
    return (unsigned short)((x + 0x7fffu + ((x >> 16) & 1u)) >> 16);
}

// ---------------------------------------------------------------------------
// fp32 tiled GEMM (kept for small/K-odd layers): C = act(A@W^T + bias*rowscale)
// ---------------------------------------------------------------------------
template<int ACT, bool RS>
__global__ __launch_bounds__(256)
void gemm_bt(const float* __restrict__ A, int lda,
             const float* __restrict__ W, int ldw,
             const float* __restrict__ bias,
             const float* __restrict__ rowscale,
             float* __restrict__ C, int ldc,
             int M, int N, int K)
{
    __shared__ float As[16][68];
    __shared__ float Ws[16][68];
    const int tid = threadIdx.x;
    const int bm = blockIdx.x * 64;
    const int bn = blockIdx.y * 64;
    const int tx = tid & 15;
    const int ty = tid >> 4;
    const int lr = tid >> 2;
    const int lk = (tid & 3) << 2;
    float acc[4][4] = {};

    for (int k0 = 0; k0 < K; k0 += 16) {
        float a0=0.f,a1=0.f,a2=0.f,a3=0.f, w0=0.f,w1=0.f,w2=0.f,w3=0.f;
        {
            const int rem = K - (k0 + lk);
            const int m = bm + lr;
            if (m < M) {
                const float* p = A + (size_t)m*lda + k0 + lk;
                if (rem > 0) a0 = p[0];
                if (rem > 1) a1 = p[1];
                if (rem > 2) a2 = p[2];
                if (rem > 3) a3 = p[3];
            }
            const int n = bn + lr;
            if (n < N) {
                const float* p = W + (size_t)n*ldw + k0 + lk;
                if (rem > 0) w0 = p[0];
                if (rem > 1) w1 = p[1];
                if (rem > 2) w2 = p[2];
                if (rem > 3) w3 = p[3];
            }
        }
        __syncthreads();
        As[lk+0][lr]=a0; As[lk+1][lr]=a1; As[lk+2][lr]=a2; As[lk+3][lr]=a3;
        Ws[lk+0][lr]=w0; Ws[lk+1][lr]=w1; Ws[lk+2][lr]=w2; Ws[lk+3][lr]=w3;
        __syncthreads();
#pragma unroll
        for (int kk = 0; kk < 16; kk++) {
            const float4 av4 = *reinterpret_cast<const float4*>(&As[kk][ty<<2]);
            const float4 wv4 = *reinterpret_cast<const float4*>(&Ws[kk][tx<<2]);
            const float av[4] = {av4.x, av4.y, av4.z, av4.w};
            const float wv[4] = {wv4.x, wv4.y, wv4.z, wv4.w};
#pragma unroll
            for (int i=0;i<4;i++)
#pragma unroll
                for (int j=0;j<4;j++)
                    acc[i][j] = fmaf(av[i], wv[j], acc[i][j]);
        }
    }
#pragma unroll
    for (int i=0;i<4;i++){
        const int m = bm + (ty<<2) + i;
        if (m >= M) continue;
        const float rs = RS ? rowscale[m] : 1.f;
#pragma unroll
        for (int j=0;j<4;j++){
            const int n = bn + (tx<<2) + j;
            if (n >= N) continue;
            float v = acc[i][j] + bias[n]*rs;
            if (ACT==1) v = leakyf(v);
            else if (ACT==2) v = v > 0.f ? v : (expf(v)-1.f);
            C[(size_t)m*ldc + n] = v;
        }
    }
}

// ---------------------------------------------------------------------------
// bf16 MFMA GEMM: C[m,n] = act( sum_k A[m,k]*W[n,k] + bias[n]*rowscale[m] )
// A [M,lda] bf16 row-major, W [N,ldw] bf16 row-major. M % 64 == 0.
// Tile 64x128, 4 waves (2x2), each wave 32x64 via 2x4 16x16x32 fragments.
// ---------------------------------------------------------------------------
template<int ACT, bool RS, bool WF32, bool WBF>
__global__ __launch_bounds__(256)
void gemm_mfma(const unsigned short* __restrict__ A, int lda,
               const unsigned short* __restrict__ W, int ldw,
               const float* __restrict__ bias,
               const float* __restrict__ rowscale,
               float* __restrict__ C, unsigned short* __restrict__ Ch, int ldc,
               int M, int N, int K)
{
    __shared__ unsigned short As[64*40];
    __shared__ unsigned short Ws[128*40];
    const int tid = threadIdx.x;
    const int bm = blockIdx.x * 64;
    const int bn = blockIdx.y * 128;
    const int wid = tid >> 6;
    const int lane = tid & 63;
    const int wm = wid >> 1;
    const int wn = wid & 1;
    const int l15 = lane & 15;
    const int kq  = lane >> 4;
    const int koff = kq * 8;

    f32x4 acc[2][4];
#pragma unroll
    for (int i=0;i<2;i++)
#pragma unroll
        for (int j=0;j<4;j++) acc[i][j] = (f32x4){0.f,0.f,0.f,0.f};

    const int sr = tid >> 2;
    const int sk = (tid & 3) * 8;

    for (int k0 = 0; k0 < K; k0 += 32) {
        uint4 av = {0,0,0,0}, wv0 = {0,0,0,0}, wv1 = {0,0,0,0};
        const int kc = k0 + sk;
        if (kc + 8 <= K) {
            av = *reinterpret_cast<const uint4*>(A + (size_t)(bm+sr)*lda + kc);
            const int n0 = bn + sr;
            if (n0 < N) wv0 = *reinterpret_cast<const uint4*>(W + (size_t)n0*ldw + kc);
            const int n1 = bn + sr + 64;
            if (n1 < N) wv1 = *reinterpret_cast<const uint4*>(W + (size_t)n1*ldw + kc);
        } else {
            __attribute__((aligned(16))) unsigned short tmp[8];
            const unsigned short* pa = A + (size_t)(bm+sr)*lda + kc;
#pragma unroll
            for (int e=0;e<8;e++) tmp[e] = (kc+e < K) ? pa[e] : (unsigned short)0;
            av = *reinterpret_cast<const uint4*>(tmp);
            const int n0 = bn + sr;
            if (n0 < N) {
                const unsigned short* pw = W + (size_t)n0*ldw + kc;
#pragma unroll
                for (int e=0;e<8;e++) tmp[e] = (kc+e<K) ? pw[e] : (unsigned short)0;
                wv0 = *reinterpret_cast<const uint4*>(tmp);
            }
            const int n1 = bn + sr + 64;
            if (n1 < N) {
                const unsigned short* pw = W + (size_t)n1*ldw + kc;
#pragma unroll
                for (int e=0;e<8;e++) tmp[e] = (kc+e<K) ? pw[e] : (unsigned short)0;
                wv1 = *reinterpret_cast<const uint4*>(tmp);
            }
        }
        __syncthreads();
        *reinterpret_cast<uint4*>(&As[sr*40 + sk]) = av;
        *reinterpret_cast<uint4*>(&Ws[sr*40 + sk]) = wv0;
        *reinterpret_cast<uint4*>(&Ws[(sr+64)*40 + sk]) = wv1;
        __syncthreads();
        short8 af[2], bfr[4];
#pragma unroll
        for (int i=0;i<2;i++)
            af[i] = *reinterpret_cast<const short8*>(&As[(wm*32 + i*16 + l15)*40 + koff]);
#pragma unroll
        for (int j=0;j<4;j++)
            bfr[j] = *reinterpret_cast<const short8*>(&Ws[(wn*64 + j*16 + l15)*40 + koff]);
#pragma unroll
        for (int i=0;i<2;i++)
#pragma unroll
            for (int j=0;j<4;j++)
                acc[i][j] = __builtin_amdgcn_mfma_f32_16x16x32_bf16(af[i], bfr[j], acc[i][j], 0, 0, 0);
    }
#pragma unroll
    for (int i=0;i<2;i++){
        const int mrow0 = bm + wm*32 + i*16 + kq*4;
#pragma unroll
        for (int j=0;j<4;j++){
            const int n = bn + wn*64 + j*16 + l15;
            if (n >= N) continue;
            const float bb = bias[n];
#pragma unroll
            for (int r=0;r<4;r++){
                const int m = mrow0 + r;
                float v = acc[i][j][r] + bb * (RS ? rowscale[m] : 1.f);
                if (ACT==1) v = leakyf(v);
                else if (ACT==2) v = v>0.f ? v : (expf(v)-1.f);
                if (WF32) C[(size_t)m*ldc + n] = v;
                if (WBF)  Ch[(size_t)m*ldc + n] = f2bf(v);
            }
        }
    }
}

// ---------------------------------------------------------------------------
__global__ __launch_bounds__(256)
void conv_bf(const float* __restrict__ src, unsigned short* __restrict__ dst, int n)
{
    const int i = blockIdx.x*blockDim.x + threadIdx.x;
    if (i < n) dst[i] = f2bf(src[i]);
}

// ---------------------------------------------------------------------------
__global__ __launch_bounds__(64)
void gather_cat(const float* __restrict__ atom_list, const float* __restrict__ bond_list,
                const int* __restrict__ adl, const int* __restrict__ bdl,
                float* __restrict__ acat)
{
    const int row = blockIdx.x;
    const int t = threadIdx.x;
    if (t >= 49) return;
    const int atom = row / 6;
    const int b = atom >> 7;
    float v;
    if (t < 39) { const int ai = adl[row]; v = atom_list[((size_t)(b*SEQL + ai))*39 + t]; }
    else        { const int bi = bdl[row]; v = bond_list[((size_t)(b*SEQL + bi))*10 + (t-39)]; }
    acat[(size_t)row*49 + t] = v;
}

// ---------------------------------------------------------------------------
// Per-atom neighbor attention; writes bf16 weighted-neighbor rows + sum of aw.
// ---------------------------------------------------------------------------
template<bool D0>
__global__ __launch_bounds__(64)
void attn_radius(const float* __restrict__ cur, const float* __restrict__ nbsrc,
                 const int* __restrict__ adl,
                 const float* __restrict__ aw_, const float* __restrict__ ab_,
                 unsigned short* __restrict__ wnbh, float* __restrict__ s_aw)
{
    const int atom = blockIdx.x;
    const int lane = threadIdx.x;
    const float* crow = cur + (size_t)atom*FPC;
    int   cc[4]; bool val[4];
    float a2[4];
    float s1p = 0.f;
#pragma unroll
    for (int r=0;r<4;r++){
        const int c = lane + 64*r; cc[r]=c; val[r] = (c < FPC);
        const float x  = val[r] ? crow[c]      : 0.f;
        const float w1 = val[r] ? aw_[c]       : 0.f;
        a2[r]          = val[r] ? aw_[FPC + c] : 0.f;
        s1p = fmaf(w1, x, s1p);
    }
    const float s1 = wave_sum(s1p);
    const int base = atom & ~(SEQL-1);
    const float ab = ab_[0];
    float nbr[NBD][4]; float score[NBD]; int idx[NBD];
#pragma unroll
    for (int j=0;j<NBD;j++){
        const int id = adl[atom*NBD + j]; idx[j]=id;
        const float* nrow = D0 ? nbsrc + ((size_t)atom*NBD + j)*FPC
                               : nbsrc + ((size_t)(base + id))*FPC;
        float s2p = 0.f;
#pragma unroll
        for (int r=0;r<4;r++){
            const float v = val[r] ? nrow[cc[r]] : 0.f;
            nbr[j][r]=v; s2p = fmaf(a2[r], v, s2p);
        }
        const float s2 = wave_sum(s2p);
        float sc = leakyf(s1 + s2 + ab);
        score[j] = sc + (id == SEQL-1 ? NEGV : 0.f);
    }
    float mx = score[0];
#pragma unroll
    for (int j=1;j<NBD;j++) mx = fmaxf(mx, score[j]);
    float e[NBD], sum = 0.f;
#pragma unroll
    for (int j=0;j<NBD;j++){ e[j] = expf(score[j]-mx); sum += e[j]; }
    const float inv = 1.f/sum;
    float w[NBD], saw = 0.f;
#pragma unroll
    for (int j=0;j<NBD;j++){ w[j] = e[j]*inv*(idx[j]==SEQL-1 ? 0.f : 1.f); saw += w[j]; }
#pragma unroll
    for (int r=0;r<4;r++){
        if (val[r]){
            float acc = 0.f;
#pragma unroll
            for (int j=0;j<NBD;j++) acc = fmaf(w[j], nbr[j][r], acc);
            wnbh[(size_t)atom*FPC + cc[r]] = f2bf(acc);
        }
    }
    if (lane==0) s_aw[atom] = saw;
}

// ---------------------------------------------------------------------------
__global__ __launch_bounds__(256)
void gru_combine(const float* __restrict__ gi, const float* __restrict__ gh,
                 float* __restrict__ h, float* __restrict__ act,
                 unsigned short* __restrict__ hh, int total)
{
    const int i = blockIdx.x*blockDim.x + threadIdx.x;
    if (i >= total) return;
    const int m = i / FPC, c = i - m*FPC;
    const size_t g = (size_t)m*600 + c;
    const float ir = gi[g], iz = gi[g+200], in_ = gi[g+400];
    const float hr = gh[g], hz = gh[g+200], hn = gh[g+400];
    const float r = 1.f/(1.f+expf(-(ir+hr)));
    const float z = 1.f/(1.f+expf(-(iz+hz)));
    const float n = tanhf(in_ + r*hn);
    const float hv = h[i];
    const float out = (1.f-z)*n + z*hv;
    h[i] = out;
    if (act) act[i] = out > 0.f ? out : 0.f;
    if (hh)  hh[i] = f2bf(out);
}

// ---------------------------------------------------------------------------
__global__ __launch_bounds__(256)
void mol_reduce(const float* __restrict__ act, const float* __restrict__ amask,
                float* __restrict__ molf, float* __restrict__ amol)
{
    const int b = blockIdx.x, c = threadIdx.x;
    if (c >= FPC) return;
    float s = 0.f;
    for (int l=0;l<SEQL;l++) s = fmaf(act[((size_t)(b*SEQL+l))*FPC + c], amask[b*SEQL+l], s);
    molf[b*FPC+c] = s;
    amol[b*FPC+c] = s > 0.f ? s : 0.f;
}

// ---------------------------------------------------------------------------
__global__ __launch_bounds__(256)
void attn_mol(const float* __restrict__ amol, const float* __restrict__ act,
              const float* __restrict__ amask,
              const float* __restrict__ maw, const float* __restrict__ mab,
              float* __restrict__ wact, float* __restrict__ s_mw)
{
    __shared__ float red[256];
    __shared__ float sc[SEQL];
    __shared__ float mw[SEQL];
    const int b = blockIdx.x, tid = threadIdx.x;
    red[tid] = (tid < FPC) ? maw[tid]*amol[b*FPC+tid] : 0.f;
    __syncthreads();
    for (int s=128; s>0; s>>=1){ if (tid < s) red[tid] += red[tid+s]; __syncthreads(); }
    const float s1 = red[0];
    __syncthreads();
    if (tid < SEQL) {
        const float* arow = act + ((size_t)(b*SEQL + tid))*FPC;
        float s2 = 0.f;
        for (int c=0;c<FPC;c++) s2 = fmaf(maw[FPC+c], arow[c], s2);
        const float am = amask[b*SEQL+tid];
        sc[tid] = leakyf(s1 + s2 + mab[0]) + (am == 0.f ? NEGV : 0.f);
    }
    __syncthreads();
    float mx = -1e30f;
    for (int l=0;l<SEQL;l++) mx = fmaxf(mx, sc[l]);
    float sum = 0.f;
    for (int l=0;l<SEQL;l++) sum += expf(sc[l]-mx);
    const float inv = 1.f/sum;
    if (tid < SEQL) mw[tid] = expf(sc[tid]-mx)*inv*amask[b*SEQL+tid];
    __syncthreads();
    float smw = 0.f;
    for (int l=0;l<SEQL;l++) smw += mw[l];
    if (tid < FPC) {
        float acc = 0.f;
        for (int l=0;l<SEQL;l++) acc = fmaf(mw[l], act[((size_t)(b*SEQL+l))*FPC + tid], acc);
        wact[b*FPC+tid] = acc;
    }
    if (tid==0) s_mw[b] = smw;
}

__global__ __launch_bounds__(64)
void out_proj(const float* __restrict__ molf, const float* __restrict__ ow,
              const float* __restrict__ ob, float* __restrict__ out)
{
    const int b = blockIdx.x, lane = threadIdx.x;
    float p = 0.f;
    for (int c=lane;c<FPC;c+=64) p = fmaf(molf[b*FPC+c], ow[c], p);
    p = wave_sum(p);
    if (lane==0) out[b] = p + ob[0];
}

__global__ __launch_bounds__(256)
void copy_f32(const float* __restrict__ src, float* __restrict__ dst, int n)
{
    const int i = blockIdx.x*blockDim.x + threadIdx.x;
    if (i < n) dst[i] = src[i];
}

// ---------------------------------------------------------------------------
extern "C" void kernel_launch(void* const* d_in, const int* in_sizes, int n_in,
                              void* d_out, int out_size, void* d_ws, size_t ws_size,
                              hipStream_t stream)
{
    const float* atom_list = (const float*)d_in[0];
    const float* bond_list = (const float*)d_in[1];
    const int*   adl       = (const int*)d_in[2];
    const int*   bdl       = (const int*)d_in[3];
    const float* amask     = (const float*)d_in[4];
    const float* atom_fc_w = (const float*)d_in[5];
    const float* atom_fc_b = (const float*)d_in[6];
    const float* nb_fc_w   = (const float*)d_in[7];
    const float* nb_fc_b   = (const float*)d_in[8];
    const float* align_w   = (const float*)d_in[9];
    const float* align_b   = (const float*)d_in[10];
    const float* attend_w  = (const float*)d_in[11];
    const float* attend_b  = (const float*)d_in[12];
    const float* gru_wih   = (const float*)d_in[13];
    const float* gru_whh   = (const float*)d_in[14];
    const float* gru_bih   = (const float*)d_in[15];
    const float* gru_bhh   = (const float*)d_in[16];
    const float* mol_align_w  = (const float*)d_in[17];
    const float* mol_align_b  = (const float*)d_in[18];
    const float* mol_attend_w = (const float*)d_in[19];
    const float* mol_attend_b = (const float*)d_in[20];
    const float* mol_gru_wih  = (const float*)d_in[21];
    const float* mol_gru_whh  = (const float*)d_in[22];
    const float* mol_gru_bih  = (const float*)d_in[23];
    const float* mol_gru_bhh  = (const float*)d_in[24];
    const float* output_w  = (const float*)d_in[25];
    const float* output_b  = (const float*)d_in[26];

    float* ws   = (float*)d_ws;
    float* h    = ws;                    // [32768,200] f32
    float* act  = h   + 6553600;         // [32768,200] f32
    float* sc   = act + 6553600;         // 6,553,600 f32 words: holds wnbh|ctxh bf16
    float* gi   = sc  + 6553600;         // [32768,600] f32
    float* gh   = gi  + 19660800;        // [32768,600] f32
    float* hhW  = gh  + 19660800;        // 3,276,800 words: hh bf16 [32768,200]
    float* s_aw = hhW + 3276800;         // [32768]
    float* molf = s_aw + 32768;
    float* amol = molf + 51200;
    float* wact = amol + 51200;
    float* s_mw = wact + 51200;
    float* mctx = s_mw + 256;
    float* mgi  = mctx + 51200;
    float* mgh  = mgi  + 153600;
    float* wend = mgh  + 153600;

    unsigned short* wnbh = (unsigned short*)sc;            // [32768,200] bf16
    unsigned short* ctxh = wnbh + 6553600;                 // [32768,200] bf16
    unsigned short* hh   = (unsigned short*)hhW;           // [32768,200] bf16
    unsigned short* wbuf = (unsigned short*)wend;          // bf16 weights
    unsigned short* w_att = wbuf;                          // 3*200*200 = 120000
    unsigned short* w_wih = wbuf + 120000;                 // 3*600*200 = 360000
    unsigned short* w_whh = wbuf + 480000;                 // 3*600*200 = 360000

    float* acat = act;                   // [196608,49] spans act+sc (dead early)
    float* nbb  = gi;                    // [196608,200] spans gi+gh (dead early)

    const dim3 blk(256);

    // weight conversions (tiny)
    conv_bf<<<(120000+255)/256, 256, 0, stream>>>(attend_w, w_att, 120000);
    conv_bf<<<(360000+255)/256, 256, 0, stream>>>(gru_wih, w_wih, 360000);
    conv_bf<<<(360000+255)/256, 256, 0, stream>>>(gru_whh, w_whh, 360000);

    // atom_feature = leaky(atom_list @ atom_fc_w.T + b) -> h (f32), then hh (bf16)
    gemm_bt<1,false><<<dim3(512,4), blk, 0, stream>>>(
        atom_list, 39, atom_fc_w, 39, atom_fc_b, nullptr, h, FPC, BL, FPC, 39);
    conv_bf<<<25600, 256, 0, stream>>>(h, hh, BL*FPC);

    // neighbor features (d=0 only), f32
    gather_cat<<<BL*NBD, 64, 0, stream>>>(atom_list, bond_list, adl, bdl, acat);
    gemm_bt<1,false><<<dim3(3072,4), blk, 0, stream>>>(
        acat, 49, nb_fc_w, 49, nb_fc_b, nullptr, nbb, FPC, BL*NBD, FPC, 49);

    for (int d=0; d<3; d++) {
        if (d==0)
            attn_radius<true ><<<BL, 64, 0, stream>>>(h,   nbb, adl, align_w,         align_b,     wnbh, s_aw);
        else
            attn_radius<false><<<BL, 64, 0, stream>>>(act, act, adl, align_w + d*400, align_b + d, wnbh, s_aw);
        // ctxh = elu(wnb @ attend_w[d].T + s_aw*attend_b[d])   (bf16 out only)
        gemm_mfma<2,true,false,true><<<dim3(512,2), blk, 0, stream>>>(
            wnbh, FPC, w_att + d*40000, FPC, attend_b + d*FPC, s_aw,
            nullptr, ctxh, FPC, BL, FPC, FPC);
        // gi = ctx @ wih.T + bih ; gh = h @ whh.T + bhh   (f32 out)
        gemm_mfma<0,false,true,false><<<dim3(512,5), blk, 0, stream>>>(
            ctxh, FPC, w_wih + d*120000, FPC, gru_bih + d*600, nullptr,
            gi, nullptr, 600, BL, 600, FPC);
        gemm_mfma<0,false,true,false><<<dim3(512,5), blk, 0, stream>>>(
            hh, FPC, w_whh + d*120000, FPC, gru_bhh + d*600, nullptr,
            gh, nullptr, 600, BL, 600, FPC);
        gru_combine<<<25600, 256, 0, stream>>>(gi, gh, h, act, hh, BL*FPC);
    }

    // molecule phase (f32)
    mol_reduce<<<BATCH, 256, 0, stream>>>(act, amask, molf, amol);
    for (int t=0; t<2; t++) {
        attn_mol<<<BATCH, 256, 0, stream>>>(amol, act, amask, mol_align_w, mol_align_b, wact, s_mw);
        gemm_bt<2,true><<<dim3(4,4), blk, 0, stream>>>(
            wact, FPC, mol_attend_w, FPC, mol_attend_b, s_mw, mctx, FPC, BATCH, FPC, FPC);
        gemm_bt<0,false><<<dim3(4,10), blk, 0, stream>>>(
            mctx, FPC, mol_gru_wih, FPC, mol_gru_bih, nullptr, mgi, 600, BATCH, 600, FPC);
        gemm_bt<0,false><<<dim3(4,10), blk, 0, stream>>>(
            molf, FPC, mol_gru_whh, FPC, mol_gru_bhh, nullptr, mgh, 600, BATCH, 600, FPC);
        gru_combine<<<200, 256, 0, stream>>>(mgi, mgh, molf, amol, nullptr, BATCH*FPC);
    }

    // outputs: atom_feature (h) then mol_prediction
    float* out = (float*)d_out;
    copy_f32<<<25600, 256, 0, stream>>>(h, out, BL*FPC);
    out_proj<<<BATCH, 64, 0, stream>>>(molf, output_w, output_b, out + BL*FPC);
}